// Round 1
// baseline (678.133 us; speedup 1.0000x reference)
//
#include <hip/hip_runtime.h>
#include <hip/hip_cooperative_groups.h>
#include <math.h>

namespace cg = cooperative_groups;

// Problem constants
#define BB   2
#define CC   256
#define HH   256
#define WW   512
#define HW   (HH*WW)        // 131072
#define IMG  (CC*HW)        // per-batch x block

// Padded prefix layout: [B][13][HPP][WPP] fp32.
// Interior rows 16..271; cols: 0..17 left pad (zeros), 18..529 interior
// inclusive row-prefix, 530..545 right pad (= row total).
#define HPP  288
#define WPP  546
#define CHPP (HPP*WPP)      // 157248
#define EVB2 (13*CHPP)      // 2044224 per batch
#define EV2_FLOATS (BB*EVB2) // 4088448 floats = 16.35 MB

// Output layout (flat concat): x_cls | x_reg | x_off
#define OUT_REG (BB*HW)     // 262144
#define OUT_OFF (2*BB*HW)   // 524288

// Log-polar region id for filter-source coords (flip folded in by caller)
static __device__ __forceinline__ int region_of(int ys, int xs) {
    int r2 = ys * ys + xs * xs;
    int bin;
    if (ys == 0)     bin = (xs >= 0) ? 0 : 2;
    else if (ys > 0) bin = (xs > 0) ? 0 : 1;
    else             bin = (xs < 0) ? 2 : 3;
    if (r2 <= 4)   return 0;
    if (r2 <= 64)  return 1 + bin;
    if (r2 <= 256) return 5 + bin;
    return 9 + bin;
}

// ---------------------------------------------------------------------------
// Phase 0 (setup): blocks 0..15 repack weights wp[c][16] + 16 biases; block 16
// builds the run-length vote table; blocks 17..68 zero the 52 top/bottom halo
// row-slabs of ev (conv writes everything else, incl. pads).
static __device__ __forceinline__ void phase_setup(
    int blk, int tid,
    const float* __restrict__ pw, const float* __restrict__ pb,
    const float* __restrict__ rw, const float* __restrict__ rb,
    const float* __restrict__ ow, const float* __restrict__ ob,
    float* __restrict__ wp, float* __restrict__ bias,
    int2* __restrict__ tabg, int* __restrict__ mg,
    float* __restrict__ ev)
{
    if (blk < 16) {
        int i = blk * 256 + tid;
        int c = i >> 4, o = i & 15;
        float v;
        if (o < 13)       v = pw[o * CC + c];
        else if (o == 13) v = rw[c];
        else              v = ow[(o - 14) * CC + c];
        wp[c * 16 + o] = v;
        if (i < 16) {
            float bv = (i < 13) ? pb[i] : (i == 13 ? rb[0] : ob[i - 14]);
            bias[i] = bv;
        }
    } else if (blk == 16) {
        __shared__ int cnt[13];
        __shared__ int runbuf[33 * 16];
        __shared__ int countrow[33];
        __shared__ int rowstart[34];
        if (tid < 13) cnt[tid] = 0;
        __syncthreads();
        for (int i = tid; i < 1089; i += 256) {
            int ky = i / 33, kx = i - ky * 33;
            atomicAdd(&cnt[region_of(16 - ky, 16 - kx)], 1);
        }
        __syncthreads();
        if (tid < 33) {
            int ky = tid, n = 0;
            int c0 = region_of(16 - ky, 16);
            int kxa = 0;
            for (int kx = 1; kx <= 33; kx++) {
                int c = (kx < 33) ? region_of(16 - ky, 16 - kx) : -1;
                if (c != c0) {
                    runbuf[tid * 16 + n] = c0 | (kxa << 4) | ((kx - 1) << 10);
                    n++;
                    c0 = c; kxa = kx;
                }
            }
            countrow[tid] = n;
        }
        __syncthreads();
        if (tid == 0) {
            int a = 0;
            for (int t = 0; t < 33; t++) { rowstart[t] = a; a += countrow[t]; }
            rowstart[33] = a;
            mg[0] = 2 * a;
        }
        __syncthreads();
        if (tid < 33) {
            int ky = tid, base = rowstart[tid], n = countrow[tid];
            for (int j = 0; j < n; j++) {
                int rn  = runbuf[tid * 16 + j];
                int c   = rn & 15, kxa = (rn >> 4) & 63, kxb = (rn >> 10) & 63;
                float w = 1.0f / (float)cnt[c];
                int off0 = c * CHPP + (ky - 16) * WPP;
                tabg[2 * (base + j)]     = make_int2(off0 + (kxb - 16), __float_as_int(w));
                tabg[2 * (base + j) + 1] = make_int2(off0 + (kxa - 17), __float_as_int(-w));
            }
        }
    } else {
        // Zero one 16-row halo slab (16*546 = 8736 floats = 2184 float4)
        int seg   = blk - 17;                 // 0..51
        int plane = seg >> 1;                 // 0..25  (b*13+ch)
        int half  = seg & 1;
        float* base = ev + (size_t)plane * CHPP + (half ? (size_t)272 * WPP : 0);
        float4 z = make_float4(0.f, 0.f, 0.f, 0.f);
        float4* b4 = (float4*)base;           // CHPP, 272*WPP both %4 == 0
#pragma unroll
        for (int it = 0; it < 9; it++) {
            int idx = it * 256 + tid;
            if (idx < 2184) b4[idx] = z;
        }
    }
}

// ---------------------------------------------------------------------------
// Phase 1: fused 1x1 convs + row prefix scan. One 256-thread block = one image
// row; thread t -> pixels (2t, 2t+1) via float2 loads (halves VMEM instr count
// vs 1 px/thread — conv was VMEM-issue-bound, not byte-bound).
// Weights via wave-uniform global reads (s_load_dwordx16). Channels 0..12 ->
// relu -> pair-sum wave scan + 4-wave LDS combine -> prefix written directly
// (left pad zeros, right pad = row total); 13 -> x_reg; 14,15 -> x_off.
static __device__ __forceinline__ void phase_conv(
    int bid, int tid,
    const float* __restrict__ x, const float* __restrict__ wp,
    const float* __restrict__ bias, float* __restrict__ ev,
    float* __restrict__ out)
{
    __shared__ float part[13][4];
    int lane = tid & 63;
    int wv   = tid >> 6;                     // 4 waves
    int b    = bid >> 8;
    int y    = bid & 255;
    int hw   = y * WW + tid * 2;
    const float* xb = x + (size_t)b * IMG + hw;

    float a0[16], a1[16];
#pragma unroll
    for (int o = 0; o < 16; o++) { a0[o] = 0.f; a1[o] = 0.f; }

#pragma unroll 4
    for (int c = 0; c < CC; c++) {
        float2 v = *(const float2*)(xb + c * HW);
        const float* wr = wp + c * 16;       // uniform -> s_load_dwordx16
#pragma unroll
        for (int o = 0; o < 16; o++) {
            float wv_ = wr[o];
            a0[o] = fmaf(v.x, wv_, a0[o]);
            a1[o] = fmaf(v.y, wv_, a1[o]);
        }
    }

    // relu+bias, pair sum, wave-inclusive scan; publish wave totals
#pragma unroll
    for (int o = 0; o < 13; o++) {
        float bo = bias[o];
        float e0 = fmaxf(a0[o] + bo, 0.f);
        float e1 = fmaxf(a1[o] + bo, 0.f);
        float s  = e0 + e1;
#pragma unroll
        for (int d = 1; d < 64; d <<= 1) {
            float t = __shfl_up(s, d, 64);
            if (lane >= d) s += t;
        }
        a0[o] = s - e1;                      // inclusive prefix through e0
        a1[o] = s;                           // inclusive prefix through e1
        if (lane == 63) part[o][wv] = s;
    }
    __syncthreads();

    size_t rowbase = (size_t)(b * 13) * CHPP + (size_t)(y + 16) * WPP;
#pragma unroll
    for (int o = 0; o < 13; o++) {
        float off = 0.f;
#pragma unroll
        for (int w2 = 0; w2 < 3; w2++)
            if (w2 < wv) off += part[o][w2];
        *(float2*)(&ev[rowbase + o * CHPP + 18 + tid * 2]) =
            make_float2(a0[o] + off, a1[o] + off);   // 8B-aligned: even offsets
    }
    // left pad zeros (cols 0..17, 13 channels = 234 stores)
    if (tid < 234) {
        int o = tid / 18, j = tid - o * 18;
        ev[rowbase + o * CHPP + j] = 0.f;
    }
    // right pad = row total (cols 530..545, 13 channels = 208 stores)
    if (tid < 208) {
        int o = tid >> 4, j = tid & 15;
        float tot = part[o][0] + part[o][1] + part[o][2] + part[o][3];
        ev[rowbase + o * CHPP + 530 + j] = tot;
    }

    *(float2*)(&out[OUT_REG + b * HW + hw]) =
        make_float2(a0[13] + bias[13], a1[13] + bias[13]);
    *(float2*)(&out[OUT_OFF + b * 2 * HW + hw]) =
        make_float2(a0[14] + bias[14], a1[14] + bias[14]);
    *(float2*)(&out[OUT_OFF + b * 2 * HW + HW + hw]) =
        make_float2(a0[15] + bias[15], a1[15] + bias[15]);
}

// ---------------------------------------------------------------------------
// Fused single-launch cooperative kernel: setup -> grid.sync -> conv+scan ->
// grid.sync -> hough. Hough phase: 512 blocks x 2 px/thread — the per-wave
// scalar table walk (330 s_load_dwordx2 + SALU addressing + loop control) is
// amortized over 2x pixels, and each unrolled group keeps 8 independent
// gathers in flight. XCD swizzle keeps each XCD's gather slab in its L2.
__global__ __launch_bounds__(256) void fused_k(
    const float* __restrict__ x,
    const float* __restrict__ pw, const float* __restrict__ pb,
    const float* __restrict__ rw, const float* __restrict__ rb,
    const float* __restrict__ ow, const float* __restrict__ ob,
    float* __restrict__ wp, float* __restrict__ bias,
    int2* __restrict__ tabg, int* __restrict__ mg,
    float* __restrict__ ev, float* __restrict__ out)
{
    int tid = threadIdx.x;
    int bid = blockIdx.x;                      // 512 blocks

    // ---- phase 0: setup (blocks 0..68) ----
    if (bid < 69)
        phase_setup(bid, tid, pw, pb, rw, rb, ow, ob, wp, bias, tabg, mg, ev);
    __threadfence();
    cg::this_grid().sync();

    // ---- phase 1: conv + scan (all 512 blocks = BB*HH rows) ----
    phase_conv(bid, tid, x, wp, bias, ev, out);
    __threadfence();
    cg::this_grid().sync();

    // ---- phase 2: hough vote + sigmoid (512 blocks x 512 px) ----
    int m   = mg[0];
    int sb  = (bid & 7) * 64 + (bid >> 3);     // XCD-contiguous pixel-block id
    int p0  = sb * 512 + tid;                  // this thread: px p0 and p0+256
    int b2  = p0 >> 17;
    int hw2 = p0 & (HW - 1);
    int y2  = hw2 >> 9, xx = hw2 & 511;        // xx in 0..255; +256 same row
    const float* Pb = ev + (size_t)b2 * EVB2 + (y2 + 16) * WPP + (xx + 18);

    float s0 = 0.f, s1 = 0.f;
#pragma unroll 4
    for (int t = 0; t < m; t++) {
        int2 e  = tabg[t];                     // uniform -> scalar load
        float w = __int_as_float(e.y);
        s0 = fmaf(Pb[e.x],       w, s0);
        s1 = fmaf(Pb[e.x + 256], w, s1);
    }
    out[b2 * HW + hw2]       = 1.0f / (1.0f + expf(-s0));
    out[b2 * HW + hw2 + 256] = 1.0f / (1.0f + expf(-s1));
}

// ---------------------------------------------------------------------------
// Fallback path (3 separate launches) in case the cooperative launch is
// rejected at capture time.
__global__ void setup_k(const float* __restrict__ pw, const float* __restrict__ pb,
                        const float* __restrict__ rw, const float* __restrict__ rb,
                        const float* __restrict__ ow, const float* __restrict__ ob,
                        float* __restrict__ wp, float* __restrict__ bias,
                        int2* __restrict__ tabg, int* __restrict__ mg,
                        float* __restrict__ ev) {
    phase_setup(blockIdx.x, threadIdx.x, pw, pb, rw, rb, ow, ob, wp, bias, tabg, mg, ev);
}

__global__ __launch_bounds__(256) void convscan_k(
    const float* __restrict__ x, const float* __restrict__ wp,
    const float* __restrict__ bias, float* __restrict__ ev,
    float* __restrict__ out) {
    phase_conv(blockIdx.x, threadIdx.x, x, wp, bias, ev, out);
}

__global__ __launch_bounds__(256) void hough_k(const float* __restrict__ P,
                                               const int2* __restrict__ tabg,
                                               const int* __restrict__ mg,
                                               float* __restrict__ out) {
    int m   = mg[0];
    int tid = threadIdx.x;
    int bid = blockIdx.x;                      // 1024 blocks
    int sb  = (bid & 7) * 128 + (bid >> 3);    // XCD-contiguous pixel-block id
    int p   = sb * 256 + tid;
    int b   = p >> 17;
    int hw  = p & (HW - 1);
    int y   = hw >> 9, xx = hw & 511;
    const float* Pb = P + (size_t)b * EVB2 + (y + 16) * WPP + (xx + 18);

    float s = 0.f;
#pragma unroll 8
    for (int t = 0; t < m; t++) {
        int2 e = tabg[t];                      // uniform -> scalar load
        s = fmaf(Pb[e.x], __int_as_float(e.y), s);
    }
    out[b * HW + hw] = 1.0f / (1.0f + expf(-s));
}

// ---------------------------------------------------------------------------
extern "C" void kernel_launch(void* const* d_in, const int* in_sizes, int n_in,
                              void* d_out, int out_size, void* d_ws, size_t ws_size,
                              hipStream_t stream) {
    const float* x  = (const float*)d_in[0];
    const float* pw = (const float*)d_in[1];
    const float* pb = (const float*)d_in[2];
    const float* rw = (const float*)d_in[3];
    const float* rb = (const float*)d_in[4];
    const float* ow = (const float*)d_in[5];
    const float* ob = (const float*)d_in[6];
    float* out = (float*)d_out;

    float* ev   = (float*)d_ws;
    float* wp   = ev + EV2_FLOATS;
    float* bias = wp + 4096;
    int2*  tabg = (int2*)(bias + 16);          // 8B-aligned (even float offset)
    int*   mg   = (int*)(tabg + 2048);

    void* kargs[] = {
        (void*)&x, (void*)&pw, (void*)&pb, (void*)&rw, (void*)&rb,
        (void*)&ow, (void*)&ob, (void*)&wp, (void*)&bias, (void*)&tabg,
        (void*)&mg, (void*)&ev, (void*)&out
    };
    hipError_t err = hipLaunchCooperativeKernel(
        reinterpret_cast<void*>(fused_k), dim3(512), dim3(256), kargs, 0, stream);
    if (err != hipSuccess) {
        (void)hipGetLastError();               // clear sticky error
        setup_k<<<69, 256, 0, stream>>>(pw, pb, rw, rb, ow, ob, wp, bias, tabg, mg, ev);
        convscan_k<<<512, 256, 0, stream>>>(x, wp, bias, ev, out);
        hough_k<<<1024, 256, 0, stream>>>(ev, tabg, mg, out);
    }
}

// Round 2
// 406.696 us; speedup vs baseline: 1.6674x; 1.6674x over previous
//
#include <hip/hip_runtime.h>
#include <math.h>

// Problem constants
#define BB   2
#define CC   256
#define HH   256
#define WW   512
#define HW   (HH*WW)        // 131072
#define IMG  (CC*HW)        // per-batch x block

// Padded prefix layout: [B][13][HPP][WPP] fp32.
// Interior rows 16..271; cols: 0..17 left pad (zeros), 18..529 interior
// inclusive row-prefix, 530..545 right pad (= row total).
#define HPP  288
#define WPP  546
#define CHPP (HPP*WPP)      // 157248
#define EVB2 (13*CHPP)      // 2044224 per batch
#define EV2_FLOATS (BB*EVB2) // 4088448 floats = 16.35 MB

// Output layout (flat concat): x_cls | x_reg | x_off
#define OUT_REG (BB*HW)     // 262144
#define OUT_OFF (2*BB*HW)   // 524288

// Log-polar region id for filter-source coords (flip folded in by caller)
static __device__ __forceinline__ int region_of(int ys, int xs) {
    int r2 = ys * ys + xs * xs;
    int bin;
    if (ys == 0)     bin = (xs >= 0) ? 0 : 2;
    else if (ys > 0) bin = (xs > 0) ? 0 : 1;
    else             bin = (xs < 0) ? 2 : 3;
    if (r2 <= 4)   return 0;
    if (r2 <= 64)  return 1 + bin;
    if (r2 <= 256) return 5 + bin;
    return 9 + bin;
}

// ---------------------------------------------------------------------------
// setup_k: blocks 0..15 repack weights wp[c][16] + 16 biases; block 16 builds
// the run-length vote table in global memory; blocks 17..68 zero the 52
// top/bottom halo row-slabs of ev (conv writes everything else, incl. pads).
__global__ void setup_k(const float* __restrict__ pw, const float* __restrict__ pb,
                        const float* __restrict__ rw, const float* __restrict__ rb,
                        const float* __restrict__ ow, const float* __restrict__ ob,
                        float* __restrict__ wp, float* __restrict__ bias,
                        int2* __restrict__ tabg, int* __restrict__ mg,
                        float* __restrict__ ev) {
    int blk = blockIdx.x, tid = threadIdx.x;
    if (blk < 16) {
        int i = blk * 256 + tid;
        int c = i >> 4, o = i & 15;
        float v;
        if (o < 13)       v = pw[o * CC + c];
        else if (o == 13) v = rw[c];
        else              v = ow[(o - 14) * CC + c];
        wp[c * 16 + o] = v;
        if (i < 16) {
            float bv = (i < 13) ? pb[i] : (i == 13 ? rb[0] : ob[i - 14]);
            bias[i] = bv;
        }
    } else if (blk == 16) {
        __shared__ int cnt[13];
        __shared__ int runbuf[33 * 16];
        __shared__ int countrow[33];
        __shared__ int rowstart[34];
        if (tid < 13) cnt[tid] = 0;
        __syncthreads();
        for (int i = tid; i < 1089; i += 256) {
            int ky = i / 33, kx = i - ky * 33;
            atomicAdd(&cnt[region_of(16 - ky, 16 - kx)], 1);
        }
        __syncthreads();
        if (tid < 33) {
            int ky = tid, n = 0;
            int c0 = region_of(16 - ky, 16);
            int kxa = 0;
            for (int kx = 1; kx <= 33; kx++) {
                int c = (kx < 33) ? region_of(16 - ky, 16 - kx) : -1;
                if (c != c0) {
                    runbuf[tid * 16 + n] = c0 | (kxa << 4) | ((kx - 1) << 10);
                    n++;
                    c0 = c; kxa = kx;
                }
            }
            countrow[tid] = n;
        }
        __syncthreads();
        if (tid == 0) {
            int a = 0;
            for (int t = 0; t < 33; t++) { rowstart[t] = a; a += countrow[t]; }
            rowstart[33] = a;
            mg[0] = 2 * a;
        }
        __syncthreads();
        if (tid < 33) {
            int ky = tid, base = rowstart[tid], n = countrow[tid];
            for (int j = 0; j < n; j++) {
                int rn  = runbuf[tid * 16 + j];
                int c   = rn & 15, kxa = (rn >> 4) & 63, kxb = (rn >> 10) & 63;
                float w = 1.0f / (float)cnt[c];
                int off0 = c * CHPP + (ky - 16) * WPP;
                tabg[2 * (base + j)]     = make_int2(off0 + (kxb - 16), __float_as_int(w));
                tabg[2 * (base + j) + 1] = make_int2(off0 + (kxa - 17), __float_as_int(-w));
            }
        }
    } else {
        // Zero one 16-row halo slab (16*546 = 8736 floats = 2184 float4)
        int seg   = blk - 17;                 // 0..51
        int plane = seg >> 1;                 // 0..25  (b*13+ch)
        int half  = seg & 1;
        float* base = ev + (size_t)plane * CHPP + (half ? (size_t)272 * WPP : 0);
        float4 z = make_float4(0.f, 0.f, 0.f, 0.f);
        float4* b4 = (float4*)base;           // CHPP, 272*WPP both %4 == 0
#pragma unroll
        for (int it = 0; it < 9; it++) {
            int idx = it * 256 + tid;
            if (idx < 2184) b4[idx] = z;
        }
    }
}

// ---------------------------------------------------------------------------
// Fused 1x1 convs + row prefix scan. One 256-thread block = one image row;
// thread t -> pixels (2t, 2t+1) via float2 loads (halves VMEM instr count vs
// 1 px/thread — conv was VMEM-issue-bound, not byte-bound).
// Weights via wave-uniform global reads (s_load_dwordx16). Channels 0..12 ->
// relu -> pair-sum wave scan + 4-wave LDS combine -> prefix written directly
// (left pad zeros, right pad = row total); 13 -> x_reg; 14,15 -> x_off.
__global__ __launch_bounds__(256) void convscan_k(
    const float* __restrict__ x, const float* __restrict__ wp,
    const float* __restrict__ bias, float* __restrict__ ev,
    float* __restrict__ out) {
    __shared__ float part[13][4];
    int tid  = threadIdx.x;                  // 0..255
    int lane = tid & 63;
    int wv   = tid >> 6;                     // 4 waves
    int bid  = blockIdx.x;                   // 512 blocks = BB*HH rows
    int b    = bid >> 8;
    int y    = bid & 255;
    int hw   = y * WW + tid * 2;
    const float* xb = x + (size_t)b * IMG + hw;

    float a0[16], a1[16];
#pragma unroll
    for (int o = 0; o < 16; o++) { a0[o] = 0.f; a1[o] = 0.f; }

#pragma unroll 4
    for (int c = 0; c < CC; c++) {
        float2 v = *(const float2*)(xb + c * HW);
        const float* wr = wp + c * 16;       // uniform -> s_load_dwordx16
#pragma unroll
        for (int o = 0; o < 16; o++) {
            float wv_ = wr[o];
            a0[o] = fmaf(v.x, wv_, a0[o]);
            a1[o] = fmaf(v.y, wv_, a1[o]);
        }
    }

    // relu+bias, pair sum, wave-inclusive scan; publish wave totals
#pragma unroll
    for (int o = 0; o < 13; o++) {
        float bo = bias[o];
        float e0 = fmaxf(a0[o] + bo, 0.f);
        float e1 = fmaxf(a1[o] + bo, 0.f);
        float s  = e0 + e1;
#pragma unroll
        for (int d = 1; d < 64; d <<= 1) {
            float t = __shfl_up(s, d, 64);
            if (lane >= d) s += t;
        }
        a0[o] = s - e1;                      // inclusive prefix through e0
        a1[o] = s;                           // inclusive prefix through e1
        if (lane == 63) part[o][wv] = s;
    }
    __syncthreads();

    size_t rowbase = (size_t)(b * 13) * CHPP + (size_t)(y + 16) * WPP;
#pragma unroll
    for (int o = 0; o < 13; o++) {
        float off = 0.f;
#pragma unroll
        for (int w2 = 0; w2 < 3; w2++)
            if (w2 < wv) off += part[o][w2];
        *(float2*)(&ev[rowbase + o * CHPP + 18 + tid * 2]) =
            make_float2(a0[o] + off, a1[o] + off);   // 8B-aligned: even offsets
    }
    // left pad zeros (cols 0..17, 13 channels = 234 stores)
    if (tid < 234) {
        int o = tid / 18, j = tid - o * 18;
        ev[rowbase + o * CHPP + j] = 0.f;
    }
    // right pad = row total (cols 530..545, 13 channels = 208 stores)
    if (tid < 208) {
        int o = tid >> 4, j = tid & 15;
        float tot = part[o][0] + part[o][1] + part[o][2] + part[o][3];
        ev[rowbase + o * CHPP + 530 + j] = tot;
    }

    *(float2*)(&out[OUT_REG + b * HW + hw]) =
        make_float2(a0[13] + bias[13], a1[13] + bias[13]);
    *(float2*)(&out[OUT_OFF + b * 2 * HW + hw]) =
        make_float2(a0[14] + bias[14], a1[14] + bias[14]);
    *(float2*)(&out[OUT_OFF + b * 2 * HW + HW + hw]) =
        make_float2(a0[15] + bias[15], a1[15] + bias[15]);
}

// ---------------------------------------------------------------------------
// Hough vote conv via run boundaries on row prefix sums + sigmoid.
// 512 blocks x 256 threads x 2 px/thread (px p and p+256, same row): the
// per-wave table walk (330 uniform scalar loads + SALU address stepping +
// loop control) is amortized over 2 pixels, and the two independent FMA
// chains double the number of gathers in flight. This phase structure was
// correctness-verified inside round-1's fused kernel.
// XCD swizzle keeps each XCD's gather slab (~2 MB) inside its 4 MiB L2.
__global__ __launch_bounds__(256) void hough_k(const float* __restrict__ P,
                                               const int2* __restrict__ tabg,
                                               const int* __restrict__ mg,
                                               float* __restrict__ out) {
    int m   = mg[0];
    int tid = threadIdx.x;
    int bid = blockIdx.x;                      // 512 blocks
    int sb  = (bid & 7) * 64 + (bid >> 3);     // XCD-contiguous pixel-block id
    int p0  = sb * 512 + tid;                  // this thread: px p0 and p0+256
    int b   = p0 >> 17;
    int hw  = p0 & (HW - 1);
    int y   = hw >> 9, xx = hw & 511;          // xx in 0..255; +256 same row
    const float* Pb = P + (size_t)b * EVB2 + (y + 16) * WPP + (xx + 18);

    float s0 = 0.f, s1 = 0.f;
#pragma unroll 4
    for (int t = 0; t < m; t++) {
        int2 e  = tabg[t];                     // uniform -> scalar load
        float w = __int_as_float(e.y);
        s0 = fmaf(Pb[e.x],       w, s0);
        s1 = fmaf(Pb[e.x + 256], w, s1);
    }
    out[b * HW + hw]       = 1.0f / (1.0f + expf(-s0));
    out[b * HW + hw + 256] = 1.0f / (1.0f + expf(-s1));
}

// ---------------------------------------------------------------------------
extern "C" void kernel_launch(void* const* d_in, const int* in_sizes, int n_in,
                              void* d_out, int out_size, void* d_ws, size_t ws_size,
                              hipStream_t stream) {
    const float* x  = (const float*)d_in[0];
    const float* pw = (const float*)d_in[1];
    const float* pb = (const float*)d_in[2];
    const float* rw = (const float*)d_in[3];
    const float* rb = (const float*)d_in[4];
    const float* ow = (const float*)d_in[5];
    const float* ob = (const float*)d_in[6];
    float* out = (float*)d_out;

    float* ev   = (float*)d_ws;
    float* wp   = ev + EV2_FLOATS;
    float* bias = wp + 4096;
    int2*  tabg = (int2*)(bias + 16);          // 8B-aligned (even float offset)
    int*   mg   = (int*)(tabg + 2048);

    setup_k<<<69, 256, 0, stream>>>(pw, pb, rw, rb, ow, ob, wp, bias, tabg, mg, ev);
    convscan_k<<<512, 256, 0, stream>>>(x, wp, bias, ev, out);
    hough_k<<<512, 256, 0, stream>>>(ev, tabg, mg, out);
}

// Round 3
// 388.418 us; speedup vs baseline: 1.7459x; 1.0471x over previous
//
#include <hip/hip_runtime.h>
#include <math.h>

// Problem constants
#define BB   2
#define CC   256
#define HH   256
#define WW   512
#define HW   (HH*WW)        // 131072
#define IMG  (CC*HW)        // per-batch x block

// Padded prefix layout: [B][13][HPP][WPP] fp32.
// Interior rows 16..271; cols: 0..17 left pad (zeros), 18..529 interior
// inclusive row-prefix, 530..545 right pad (= row total).
#define HPP  288
#define WPP  546
#define CHPP (HPP*WPP)      // 157248
#define EVB2 (13*CHPP)      // 2044224 per batch
#define EV2_FLOATS (BB*EVB2) // 4088448 floats = 16.35 MB

// Output layout (flat concat): x_cls | x_reg | x_off
#define OUT_REG (BB*HW)     // 262144
#define OUT_OFF (2*BB*HW)   // 524288

// Log-polar region id for filter-source coords (flip folded in by caller)
static __device__ __forceinline__ int region_of(int ys, int xs) {
    int r2 = ys * ys + xs * xs;
    int bin;
    if (ys == 0)     bin = (xs >= 0) ? 0 : 2;
    else if (ys > 0) bin = (xs > 0) ? 0 : 1;
    else             bin = (xs < 0) ? 2 : 3;
    if (r2 <= 4)   return 0;
    if (r2 <= 64)  return 1 + bin;
    if (r2 <= 256) return 5 + bin;
    return 9 + bin;
}

// ---------------------------------------------------------------------------
// setup_k (16 blocks): repack weights wp[c][16] + 16 biases only. The halo
// zeroing and vote-table build moved into convscan_k's grid (they produce
// only hough inputs, so the convscan->hough kernel boundary orders them).
__global__ void setup_k(const float* __restrict__ pw, const float* __restrict__ pb,
                        const float* __restrict__ rw, const float* __restrict__ rb,
                        const float* __restrict__ ow, const float* __restrict__ ob,
                        float* __restrict__ wp, float* __restrict__ bias) {
    int i = blockIdx.x * 256 + threadIdx.x;
    int c = i >> 4, o = i & 15;
    float v;
    if (o < 13)       v = pw[o * CC + c];
    else if (o == 13) v = rw[c];
    else              v = ow[(o - 14) * CC + c];
    wp[c * 16 + o] = v;
    if (i < 16) {
        float bv = (i < 13) ? pb[i] : (i == 13 ? rb[0] : ob[i - 14]);
        bias[i] = bv;
    }
}

// ---------------------------------------------------------------------------
// convscan_k, grid = 565 blocks:
//   bid 0      : build run-length vote table (hough input)
//   bid 1..52  : zero the 52 top/bottom halo row-slabs of ev (hough input)
//   bid 53..564: fused 1x1 convs + row prefix scan, one block per image row.
// The 53 aux blocks are placed first so they dispatch before the conv wave
// and ride free under conv's memory-bound phase.
//
// Conv path: thread t -> pixels (2t, 2t+1) via float2 loads (halves VMEM
// instr count vs 1 px/thread — conv is VMEM-issue/HBM-bound, not byte-bound).
// Weights via wave-uniform global reads (s_load_dwordx16). Channels 0..12 ->
// relu -> pair-sum wave scan + 4-wave LDS combine -> prefix written directly
// (left pad zeros, right pad = row total); 13 -> x_reg; 14,15 -> x_off.
__global__ __launch_bounds__(256) void convscan_k(
    const float* __restrict__ x, const float* __restrict__ wp,
    const float* __restrict__ bias, float* __restrict__ ev,
    int2* __restrict__ tabg, int* __restrict__ mg,
    float* __restrict__ out) {
    __shared__ float part[13][4];
    int tid = threadIdx.x;                   // 0..255
    int bid = blockIdx.x;

    if (bid == 0) {
        // ---- vote-table build (identical logic to the old setup_k blk 16) ----
        __shared__ int cnt[13];
        __shared__ int runbuf[33 * 16];
        __shared__ int countrow[33];
        __shared__ int rowstart[34];
        if (tid < 13) cnt[tid] = 0;
        __syncthreads();
        for (int i = tid; i < 1089; i += 256) {
            int ky = i / 33, kx = i - ky * 33;
            atomicAdd(&cnt[region_of(16 - ky, 16 - kx)], 1);
        }
        __syncthreads();
        if (tid < 33) {
            int ky = tid, n = 0;
            int c0 = region_of(16 - ky, 16);
            int kxa = 0;
            for (int kx = 1; kx <= 33; kx++) {
                int c = (kx < 33) ? region_of(16 - ky, 16 - kx) : -1;
                if (c != c0) {
                    runbuf[tid * 16 + n] = c0 | (kxa << 4) | ((kx - 1) << 10);
                    n++;
                    c0 = c; kxa = kx;
                }
            }
            countrow[tid] = n;
        }
        __syncthreads();
        if (tid == 0) {
            int a = 0;
            for (int t = 0; t < 33; t++) { rowstart[t] = a; a += countrow[t]; }
            rowstart[33] = a;
            mg[0] = 2 * a;
        }
        __syncthreads();
        if (tid < 33) {
            int ky = tid, base = rowstart[tid], n = countrow[tid];
            for (int j = 0; j < n; j++) {
                int rn  = runbuf[tid * 16 + j];
                int c   = rn & 15, kxa = (rn >> 4) & 63, kxb = (rn >> 10) & 63;
                float w = 1.0f / (float)cnt[c];
                int off0 = c * CHPP + (ky - 16) * WPP;
                tabg[2 * (base + j)]     = make_int2(off0 + (kxb - 16), __float_as_int(w));
                tabg[2 * (base + j) + 1] = make_int2(off0 + (kxa - 17), __float_as_int(-w));
            }
        }
        return;
    }
    if (bid < 53) {
        // ---- zero one 16-row halo slab (16*546 = 8736 floats = 2184 float4) ----
        int seg   = bid - 1;                  // 0..51
        int plane = seg >> 1;                 // 0..25  (b*13+ch)
        int half  = seg & 1;
        float* base = ev + (size_t)plane * CHPP + (half ? (size_t)272 * WPP : 0);
        float4 z = make_float4(0.f, 0.f, 0.f, 0.f);
        float4* b4 = (float4*)base;           // CHPP, 272*WPP both %4 == 0
#pragma unroll
        for (int it = 0; it < 9; it++) {
            int idx = it * 256 + tid;
            if (idx < 2184) b4[idx] = z;
        }
        return;
    }

    // ---- conv + scan path ----
    int lane = tid & 63;
    int wv   = tid >> 6;                     // 4 waves
    int row  = bid - 53;                     // 0..511 = BB*HH rows
    int b    = row >> 8;
    int y    = row & 255;
    int hw   = y * WW + tid * 2;
    const float* xb = x + (size_t)b * IMG + hw;

    float a0[16], a1[16];
#pragma unroll
    for (int o = 0; o < 16; o++) { a0[o] = 0.f; a1[o] = 0.f; }

#pragma unroll 4
    for (int c = 0; c < CC; c++) {
        float2 v = *(const float2*)(xb + c * HW);
        const float* wr = wp + c * 16;       // uniform -> s_load_dwordx16
#pragma unroll
        for (int o = 0; o < 16; o++) {
            float wv_ = wr[o];
            a0[o] = fmaf(v.x, wv_, a0[o]);
            a1[o] = fmaf(v.y, wv_, a1[o]);
        }
    }

    // relu+bias, pair sum, wave-inclusive scan; publish wave totals
#pragma unroll
    for (int o = 0; o < 13; o++) {
        float bo = bias[o];
        float e0 = fmaxf(a0[o] + bo, 0.f);
        float e1 = fmaxf(a1[o] + bo, 0.f);
        float s  = e0 + e1;
#pragma unroll
        for (int d = 1; d < 64; d <<= 1) {
            float t = __shfl_up(s, d, 64);
            if (lane >= d) s += t;
        }
        a0[o] = s - e1;                      // inclusive prefix through e0
        a1[o] = s;                           // inclusive prefix through e1
        if (lane == 63) part[o][wv] = s;
    }
    __syncthreads();

    size_t rowbase = (size_t)(b * 13) * CHPP + (size_t)(y + 16) * WPP;
#pragma unroll
    for (int o = 0; o < 13; o++) {
        float off = 0.f;
#pragma unroll
        for (int w2 = 0; w2 < 3; w2++)
            if (w2 < wv) off += part[o][w2];
        *(float2*)(&ev[rowbase + o * CHPP + 18 + tid * 2]) =
            make_float2(a0[o] + off, a1[o] + off);   // 8B-aligned: even offsets
    }
    // left pad zeros (cols 0..17, 13 channels = 234 stores)
    if (tid < 234) {
        int o = tid / 18, j = tid - o * 18;
        ev[rowbase + o * CHPP + j] = 0.f;
    }
    // right pad = row total (cols 530..545, 13 channels = 208 stores)
    if (tid < 208) {
        int o = tid >> 4, j = tid & 15;
        float tot = part[o][0] + part[o][1] + part[o][2] + part[o][3];
        ev[rowbase + o * CHPP + 530 + j] = tot;
    }

    *(float2*)(&out[OUT_REG + b * HW + hw]) =
        make_float2(a0[13] + bias[13], a1[13] + bias[13]);
    *(float2*)(&out[OUT_OFF + b * 2 * HW + hw]) =
        make_float2(a0[14] + bias[14], a1[14] + bias[14]);
    *(float2*)(&out[OUT_OFF + b * 2 * HW + HW + hw]) =
        make_float2(a0[15] + bias[15], a1[15] + bias[15]);
}

// ---------------------------------------------------------------------------
// Hough vote conv via run boundaries on row prefix sums + sigmoid.
// Round-0 verified geometry: 1024 blocks x 256 threads x 1 px/thread —
// latency-bound gather wants max waves (16/CU), not per-thread ILP (the
// 512x2px variant measured +11 us). Table entries via uniform scalar loads;
// 1 vector load + 1 FMA per entry. XCD swizzle keeps each XCD's gather slab
// (~2 MB) inside its 4 MiB L2.
__global__ __launch_bounds__(256) void hough_k(const float* __restrict__ P,
                                               const int2* __restrict__ tabg,
                                               const int* __restrict__ mg,
                                               float* __restrict__ out) {
    int m   = mg[0];
    int tid = threadIdx.x;
    int bid = blockIdx.x;                      // 1024 blocks
    int sb  = (bid & 7) * 128 + (bid >> 3);    // XCD-contiguous pixel-block id
    int p   = sb * 256 + tid;
    int b   = p >> 17;
    int hw  = p & (HW - 1);
    int y   = hw >> 9, xx = hw & 511;
    const float* Pb = P + (size_t)b * EVB2 + (y + 16) * WPP + (xx + 18);

    float s = 0.f;
#pragma unroll 8
    for (int t = 0; t < m; t++) {
        int2 e = tabg[t];                      // uniform -> scalar load
        s = fmaf(Pb[e.x], __int_as_float(e.y), s);
    }
    out[b * HW + hw] = 1.0f / (1.0f + expf(-s));
}

// ---------------------------------------------------------------------------
extern "C" void kernel_launch(void* const* d_in, const int* in_sizes, int n_in,
                              void* d_out, int out_size, void* d_ws, size_t ws_size,
                              hipStream_t stream) {
    const float* x  = (const float*)d_in[0];
    const float* pw = (const float*)d_in[1];
    const float* pb = (const float*)d_in[2];
    const float* rw = (const float*)d_in[3];
    const float* rb = (const float*)d_in[4];
    const float* ow = (const float*)d_in[5];
    const float* ob = (const float*)d_in[6];
    float* out = (float*)d_out;

    float* ev   = (float*)d_ws;
    float* wp   = ev + EV2_FLOATS;
    float* bias = wp + 4096;
    int2*  tabg = (int2*)(bias + 16);          // 8B-aligned (even float offset)
    int*   mg   = (int*)(tabg + 2048);

    setup_k<<<16, 256, 0, stream>>>(pw, pb, rw, rb, ow, ob, wp, bias);
    convscan_k<<<565, 256, 0, stream>>>(x, wp, bias, ev, tabg, mg, out);
    hough_k<<<1024, 256, 0, stream>>>(ev, tabg, mg, out);
}